// Round 4
// baseline (259.966 us; speedup 1.0000x reference)
//
#include <hip/hip_runtime.h>

// Shapes (fixed):
//   prev/next: [8, 32, 48, 48, 48] f32
//   phi:       [8, 1, 96, 96, 96] f32
//   stream:    [8, 3, 96, 96, 96] f32
// Outputs concatenated in d_out (f32): corr [8,27,48^3], vel/vel_phi/vel_stream [8,3,94^3]
//
// R3 diagnosis: vmem-instruction-throughput bound (hbm 26%, VALU 10%).
// R4: fewer, wider vmem ops. corr: y-block2 + f4-z (14 loads / 8 outputs).
// vel: t-block4 (36 loads / 4 outputs), ragged t=92..93 in its own segment.

typedef float f2 __attribute__((ext_vector_type(2)));
typedef float f4 __attribute__((ext_vector_type(4)));
typedef float f4u __attribute__((ext_vector_type(4), aligned(8)));  // stores: 8B-aligned only

constexpr int CB = 8, CC = 32, CX = 48, CY = 48, CZ = 48;
constexpr int H = 96, O = 94;
constexpr int PLANE = CY * CZ;        // 2304
constexpr int CSTR  = CX * PLANE;     // 110592
constexpr int HP    = H * H;          // 9216

constexpr int CORR_NWG   = (CB * CX * (CY / 2) * (CZ / 4)) / 256;  // 432 (exact)
constexpr int VELM_TOTAL = CB * O * O * 23;                        // 1,625,824 (t=0..91)
constexpr int VELM_NWG   = (VELM_TOTAL + 255) / 256;               // 6351
constexpr int VELT_TOTAL = CB * O * O;                             // 70,688 (t=92,93)
constexpr int VELT_NWG   = (VELT_TOTAL + 255) / 256;               // 277

// ---------------------------------------------------------------------------
// corr: thread owns (b, x, y0..y0+1, z4*4..z4*4+3). Per c: 2 prev f4 + 12 nxt
// f4 rows; interior rows feed 2 dy-taps. Invalid rows use clamped (safe)
// pointers; their taps are zeroed once in the epilogue.
// ---------------------------------------------------------------------------
__device__ __forceinline__ void corr_body(
    int bid, const float* __restrict__ prev, const float* __restrict__ nxt,
    float* __restrict__ corr)
{
    constexpr int Z4 = CZ / 4, YG = CY / 2;          // 12, 24
    int swz = (bid & 7) * (CORR_NWG / 8) + (bid >> 3);  // XCD k -> batch b = k
    int idx = swz * 256 + (int)threadIdx.x;
    int z4 = idx % Z4; int r = idx / Z4;
    int yg = r % YG; r /= YG;
    int x = r % CX; int b = r / CX;
    const int y0 = yg * 2;

    const size_t bbase = (size_t)b * CC * CSTR;
    const float* pp = prev + bbase + (size_t)x * PLANE + (size_t)y0 * CZ + z4 * 4;

    const float* rp[3][4];
    bool vr[3][4];
#pragma unroll
    for (int a = 0; a < 3; ++a) {
        int xx = x - 1 + a;
        bool vx = (unsigned)xx < (unsigned)CX;
#pragma unroll
        for (int rw = 0; rw < 4; ++rw) {
            int yy = y0 - 1 + rw;
            bool v = vx && ((unsigned)yy < (unsigned)CY);
            vr[a][rw] = v;
            rp[a][rw] = nxt + bbase + (size_t)(v ? xx : x) * PLANE
                                    + (size_t)(v ? yy : y0) * CZ + z4 * 4;
        }
    }

    f4 acc[9][2];
#pragma unroll
    for (int jj = 0; jj < 9; ++jj) { acc[jj][0] = f4{0,0,0,0}; acc[jj][1] = f4{0,0,0,0}; }

#pragma unroll 2
    for (int c = 0; c < CC; ++c) {
        f4 p0 = *reinterpret_cast<const f4*>(pp);
        f4 p1 = *reinterpret_cast<const f4*>(pp + CZ);   // imm offset +192B
#pragma unroll
        for (int a = 0; a < 3; ++a) {
            f4 n0 = *reinterpret_cast<const f4*>(rp[a][0]);
            f4 n1 = *reinterpret_cast<const f4*>(rp[a][1]);
            f4 n2 = *reinterpret_cast<const f4*>(rp[a][2]);
            f4 n3 = *reinterpret_cast<const f4*>(rp[a][3]);
            acc[a*3+0][0] += p0 * n0;
            acc[a*3+1][0] += p0 * n1;  acc[a*3+0][1] += p1 * n1;
            acc[a*3+2][0] += p0 * n2;  acc[a*3+1][1] += p1 * n2;
                                       acc[a*3+2][1] += p1 * n3;
            rp[a][0] += CSTR; rp[a][1] += CSTR; rp[a][2] += CSTR; rp[a][3] += CSTR;
        }
        pp += CSTR;
    }

#pragma unroll
    for (int l = 0; l < 2; ++l) {
        float* ob = corr + (size_t)b * 27 * CSTR + (size_t)x * PLANE
                  + (size_t)(y0 + l) * CZ + z4 * 4;
#pragma unroll
        for (int jj = 0; jj < 9; ++jj) {
            const int a = jj / 3, d = jj % 3;
            const float sc = vr[a][l + d] ? (1.0f / 32.0f) : 0.0f;
            f4 v = acc[jj][l] * sc;
            f4 gm = v; if (z4 == Z4 - 1) gm.w = 0.f;     // k=-1: zero z==47
            f4 gp = v; if (z4 == 0)      gp.x = 0.f;     // k=+1: zero z==0
            __builtin_nontemporal_store(gm, (f4*)(ob + (size_t)jj * CSTR));
            __builtin_nontemporal_store(v,  (f4*)(ob + (size_t)(9 + jj) * CSTR));
            __builtin_nontemporal_store(gp, (f4*)(ob + (size_t)(18 + jj) * CSTR));
        }
    }
}

// ---------------------------------------------------------------------------
// vel main: thread owns 4 t-outputs (t = 4*tt, tt<23). Each of 18 stencil rows
// loaded as aligned f4 (t..t+3) + f2 (t+4..t+5). All accesses in-bounds
// (max index t+5 = 96 -> t<=90; here t<=88).
// ---------------------------------------------------------------------------
struct R8 { f4 a; f2 b; };
__device__ __forceinline__ R8 ld8(const float* p) {
    R8 r; r.a = *reinterpret_cast<const f4*>(p);
    r.b = *reinterpret_cast<const f2*>(p + 4); return r;
}
__device__ __forceinline__ float at8(const R8& r, int e) {   // e must be unroll-const
    return e < 4 ? r.a[e] : r.b[e - 4];
}

__device__ __forceinline__ void velm_body(
    int bid, const float* __restrict__ phi, const float* __restrict__ stm,
    float* __restrict__ vel, float* __restrict__ vphi, float* __restrict__ vstr)
{
    const int q = VELM_NWG >> 3, rr = VELM_NWG & 7;  // 793, 7
    int xcd = bid & 7, g = bid >> 3;
    int swz = (xcd < rr) ? (xcd * (q + 1) + g) : (rr * (q + 1) + (xcd - rr) * q + g);
    int idx = swz * 256 + (int)threadIdx.x;
    if (idx >= VELM_TOTAL) return;
    int tt = idx % 23; int r2 = idx / 23;
    int j = r2 % O; r2 /= O;
    int i = r2 % O; int b = r2 / O;
    const int t = 4 * tt;

    const size_t hc = (size_t)H * HP;
    const float* ph = phi + (size_t)b * hc;
    const float* s0 = stm + (size_t)b * 3 * hc;
    const float* s1 = s0 + hc;
    const float* s2 = s1 + hc;
    const size_t ctr = (size_t)(i + 1) * HP + (size_t)(j + 1) * H + t;

    // ---- phi ----
    R8 c11 = ld8(ph + ctr);
    R8 r12 = ld8(ph + ctr + H);
    R8 r10 = ld8(ph + ctr - H);
    R8 r21 = ld8(ph + ctr + HP);
    R8 r01 = ld8(ph + ctr - HP);
    float mup[4], mvp[4], mwp[4];
#pragma unroll
    for (int o = 0; o < 4; ++o) {
        mup[o] = (at8(c11, o + 2) - at8(c11, o)) * 0.5f;
        mvp[o] = (at8(r12, o + 1) - at8(r10, o + 1)) * 0.5f;
        mwp[o] = (at8(r21, o + 1) - at8(r01, o + 1)) * 0.5f;
    }

    // ---- u = d_x s1 - d_y s0 ----
    R8 b1_21 = ld8(s1 + ctr + HP);
    R8 b1_11 = ld8(s1 + ctr);
    R8 b0_12 = ld8(s0 + ctr + H);
    R8 b0_11 = ld8(s0 + ctr);
    float u[5];
#pragma unroll
    for (int k = 0; k < 5; ++k)
        u[k] = (at8(b1_21, k) - at8(b1_11, k)) - (at8(b0_12, k) - at8(b0_11, k));
    float mus[4];
#pragma unroll
    for (int o = 0; o < 4; ++o) mus[o] = (u[o + 1] + u[o]) * 0.5f;

    // ---- v = d_t s0 - d_x s2 ----
    R8 b0_10 = ld8(s0 + ctr - H);
    R8 b2_21 = ld8(s2 + ctr + HP);
    R8 b2_11 = ld8(s2 + ctr);
    R8 b2_20 = ld8(s2 + ctr + HP - H);
    R8 b2_10 = ld8(s2 + ctr - H);
    float mvs[4];
#pragma unroll
    for (int o = 0; o < 4; ++o) {
        float v1 = (at8(b0_11, o + 2) - at8(b0_11, o + 1)) - (at8(b2_21, o + 1) - at8(b2_11, o + 1));
        float v0 = (at8(b0_10, o + 2) - at8(b0_10, o + 1)) - (at8(b2_20, o + 1) - at8(b2_10, o + 1));
        mvs[o] = (v1 + v0) * 0.5f;
    }

    // ---- w = d_y s2 - d_t s1 ----
    R8 b2_12 = ld8(s2 + ctr + H);
    R8 b2_02 = ld8(s2 + ctr - HP + H);
    R8 b2_01 = ld8(s2 + ctr - HP);
    R8 b1_01 = ld8(s1 + ctr - HP);
    float mws[4];
#pragma unroll
    for (int o = 0; o < 4; ++o) {
        float w1 = (at8(b2_12, o + 1) - at8(b2_11, o + 1)) - (at8(b1_11, o + 2) - at8(b1_11, o + 1));
        float w0 = (at8(b2_02, o + 1) - at8(b2_01, o + 1)) - (at8(b1_01, o + 2) - at8(b1_01, o + 1));
        mws[o] = (w1 + w0) * 0.5f;
    }

    const size_t oc = (size_t)O * O * O;
    const size_t oo = ((size_t)i * O + j) * O + t;
    const size_t b3 = (size_t)b * 3;
    __builtin_nontemporal_store(f4u{mup[0], mup[1], mup[2], mup[3]}, (f4u*)(vphi + (b3 + 0) * oc + oo));
    __builtin_nontemporal_store(f4u{mvp[0], mvp[1], mvp[2], mvp[3]}, (f4u*)(vphi + (b3 + 1) * oc + oo));
    __builtin_nontemporal_store(f4u{mwp[0], mwp[1], mwp[2], mwp[3]}, (f4u*)(vphi + (b3 + 2) * oc + oo));
    __builtin_nontemporal_store(f4u{mus[0], mus[1], mus[2], mus[3]}, (f4u*)(vstr + (b3 + 0) * oc + oo));
    __builtin_nontemporal_store(f4u{mvs[0], mvs[1], mvs[2], mvs[3]}, (f4u*)(vstr + (b3 + 1) * oc + oo));
    __builtin_nontemporal_store(f4u{mws[0], mws[1], mws[2], mws[3]}, (f4u*)(vstr + (b3 + 2) * oc + oo));
    __builtin_nontemporal_store(f4u{mup[0] + mus[0], mup[1] + mus[1], mup[2] + mus[2], mup[3] + mus[3]},
                                (f4u*)(vel + (b3 + 0) * oc + oo));
    __builtin_nontemporal_store(f4u{mvp[0] + mvs[0], mvp[1] + mvs[1], mvp[2] + mvs[2], mvp[3] + mvs[3]},
                                (f4u*)(vel + (b3 + 1) * oc + oo));
    __builtin_nontemporal_store(f4u{mwp[0] + mws[0], mwp[1] + mws[1], mwp[2] + mws[2], mwp[3] + mws[3]},
                                (f4u*)(vel + (b3 + 2) * oc + oo));
}

// ---------------------------------------------------------------------------
// vel tail: t = 92,93 (2 outputs). Windows 92..95 -> single aligned f4 per row.
// ---------------------------------------------------------------------------
__device__ __forceinline__ void velt_body(
    int bid, const float* __restrict__ phi, const float* __restrict__ stm,
    float* __restrict__ vel, float* __restrict__ vphi, float* __restrict__ vstr)
{
    int idx = bid * 256 + (int)threadIdx.x;
    if (idx >= VELT_TOTAL) return;
    int j = idx % O; int r2 = idx / O;
    int i = r2 % O; int b = r2 / O;
    const int t = 92;

    const size_t hc = (size_t)H * HP;
    const float* ph = phi + (size_t)b * hc;
    const float* s0 = stm + (size_t)b * 3 * hc;
    const float* s1 = s0 + hc;
    const float* s2 = s1 + hc;
    const size_t ctr = (size_t)(i + 1) * HP + (size_t)(j + 1) * H + t;

#define L4(p) (*reinterpret_cast<const f4*>(p))
    f4 c11 = L4(ph + ctr), r12 = L4(ph + ctr + H), r10 = L4(ph + ctr - H);
    f4 r21 = L4(ph + ctr + HP), r01 = L4(ph + ctr - HP);
    f4 b1_21 = L4(s1 + ctr + HP), b1_11 = L4(s1 + ctr), b1_01 = L4(s1 + ctr - HP);
    f4 b0_12 = L4(s0 + ctr + H), b0_11 = L4(s0 + ctr), b0_10 = L4(s0 + ctr - H);
    f4 b2_21 = L4(s2 + ctr + HP), b2_11 = L4(s2 + ctr), b2_20 = L4(s2 + ctr + HP - H);
    f4 b2_10 = L4(s2 + ctr - H), b2_12 = L4(s2 + ctr + H), b2_02 = L4(s2 + ctr - HP + H);
    f4 b2_01 = L4(s2 + ctr - HP);
#undef L4

    float mup[2], mvp[2], mwp[2], mus[2], mvs[2], mws[2];
    float u[3];
#pragma unroll
    for (int k = 0; k < 3; ++k)
        u[k] = (b1_21[k] - b1_11[k]) - (b0_12[k] - b0_11[k]);
#pragma unroll
    for (int o = 0; o < 2; ++o) {
        mup[o] = (c11[o + 2] - c11[o]) * 0.5f;
        mvp[o] = (r12[o + 1] - r10[o + 1]) * 0.5f;
        mwp[o] = (r21[o + 1] - r01[o + 1]) * 0.5f;
        mus[o] = (u[o + 1] + u[o]) * 0.5f;
        float v1 = (b0_11[o + 2] - b0_11[o + 1]) - (b2_21[o + 1] - b2_11[o + 1]);
        float v0 = (b0_10[o + 2] - b0_10[o + 1]) - (b2_20[o + 1] - b2_10[o + 1]);
        mvs[o] = (v1 + v0) * 0.5f;
        float w1 = (b2_12[o + 1] - b2_11[o + 1]) - (b1_11[o + 2] - b1_11[o + 1]);
        float w0 = (b2_02[o + 1] - b2_01[o + 1]) - (b1_01[o + 2] - b1_01[o + 1]);
        mws[o] = (w1 + w0) * 0.5f;
    }

    const size_t oc = (size_t)O * O * O;
    const size_t oo = ((size_t)i * O + j) * O + t;
    const size_t b3 = (size_t)b * 3;
    __builtin_nontemporal_store(f2{mup[0], mup[1]}, (f2*)(vphi + (b3 + 0) * oc + oo));
    __builtin_nontemporal_store(f2{mvp[0], mvp[1]}, (f2*)(vphi + (b3 + 1) * oc + oo));
    __builtin_nontemporal_store(f2{mwp[0], mwp[1]}, (f2*)(vphi + (b3 + 2) * oc + oo));
    __builtin_nontemporal_store(f2{mus[0], mus[1]}, (f2*)(vstr + (b3 + 0) * oc + oo));
    __builtin_nontemporal_store(f2{mvs[0], mvs[1]}, (f2*)(vstr + (b3 + 1) * oc + oo));
    __builtin_nontemporal_store(f2{mws[0], mws[1]}, (f2*)(vstr + (b3 + 2) * oc + oo));
    __builtin_nontemporal_store(f2{mup[0] + mus[0], mup[1] + mus[1]}, (f2*)(vel + (b3 + 0) * oc + oo));
    __builtin_nontemporal_store(f2{mvp[0] + mvs[0], mvp[1] + mvs[1]}, (f2*)(vel + (b3 + 1) * oc + oo));
    __builtin_nontemporal_store(f2{mwp[0] + mws[0], mwp[1] + mws[1]}, (f2*)(vel + (b3 + 2) * oc + oo));
}

__global__ __launch_bounds__(256) void fused_kernel(
    const float* __restrict__ prev, const float* __restrict__ nxt,
    const float* __restrict__ phi, const float* __restrict__ stm,
    float* __restrict__ corr, float* __restrict__ vel,
    float* __restrict__ vphi, float* __restrict__ vstr)
{
    int bid = blockIdx.x;
    if (bid < CORR_NWG) {
        corr_body(bid, prev, nxt, corr);
    } else if (bid < CORR_NWG + VELM_NWG) {
        velm_body(bid - CORR_NWG, phi, stm, vel, vphi, vstr);
    } else {
        velt_body(bid - CORR_NWG - VELM_NWG, phi, stm, vel, vphi, vstr);
    }
}

extern "C" void kernel_launch(void* const* d_in, const int* in_sizes, int n_in,
                              void* d_out, int out_size, void* d_ws, size_t ws_size,
                              hipStream_t stream)
{
    const float* prev = (const float*)d_in[0];
    const float* nxt  = (const float*)d_in[1];
    const float* phi  = (const float*)d_in[2];
    const float* stm  = (const float*)d_in[3];

    float* out = (float*)d_out;
    const size_t corr_sz = (size_t)CB * 27 * CX * CY * CZ;   // 23,887,872
    const size_t vel_sz  = (size_t)CB * 3 * O * O * O;       // 19,934,016
    float* corr = out;
    float* vel  = out + corr_sz;
    float* vphi = vel + vel_sz;
    float* vstr = vphi + vel_sz;

    fused_kernel<<<CORR_NWG + VELM_NWG + VELT_NWG, 256, 0, stream>>>(
        prev, nxt, phi, stm, corr, vel, vphi, vstr);
}

// Round 5
// 227.396 us; speedup vs baseline: 1.1432x; 1.1432x over previous
//
#include <hip/hip_runtime.h>

// Shapes (fixed):
//   prev/next: [8, 32, 48, 48, 48] f32
//   phi:       [8, 1, 96, 96, 96] f32
//   stream:    [8, 3, 96, 96, 96] f32
// Outputs concatenated in d_out (f32): corr [8,27,48^3], vel/vel_phi/vel_stream [8,3,94^3]
//
// R5: EXACT R3 kernel (208 us) with ONE change: nontemporal stores -> normal
// stores. A/B test of the nt-store path (writes ran at a constant ~1.4 TB/s
// across R2/R3/R4 while the fill kernel does 7 TB/s with normal stores).

typedef float f2 __attribute__((ext_vector_type(2)));

constexpr int CB = 8, CC = 32, CX = 48, CY = 48, CZ = 48;
constexpr int H = 96, O = 94;

constexpr int CORR_NWG = (CB * CX * CY * (CZ / 2)) / 256;    // 1728
constexpr int VEL_TOTAL = CB * O * O * (O / 2);              // 3,322,336
constexpr int VEL_NWG = (VEL_TOTAL + 255) / 256;             // 12978

__device__ __forceinline__ void corr_body(
    int bid, const float* __restrict__ prev, const float* __restrict__ nxt,
    float* __restrict__ corr)
{
    constexpr int Z2 = CZ / 2;                       // 24
    int swz = (bid & 7) * (CORR_NWG / 8) + (bid >> 3);  // XCD k -> batch b = k
    int idx = swz * 256 + (int)threadIdx.x;
    int z2 = idx % Z2; int r = idx / Z2;
    int y = r % CY; r /= CY;
    int x = r % CX; int b = r / CX;

    const int plane = CY * CZ;                       // 2304
    const int cstr  = CX * plane;                    // 110592
    const size_t bbase = (size_t)b * CC * cstr;

    const float* pp = prev + bbase + (size_t)x * plane + (size_t)y * CZ + z2 * 2;

    const float* tpx[3];
    bool okx[3], oky[3];
#pragma unroll
    for (int d = 0; d < 3; ++d) {
        int xx = x + d - 1;
        okx[d] = (unsigned)xx < (unsigned)CX;
        tpx[d] = nxt + bbase + (size_t)(okx[d] ? xx : x) * plane
                             + (size_t)y * CZ + z2 * 2;
        int yy = y + d - 1;
        oky[d] = (unsigned)yy < (unsigned)CY;
    }
    bool okj[9];
#pragma unroll
    for (int a = 0; a < 3; ++a)
#pragma unroll
        for (int dyy = 0; dyy < 3; ++dyy) okj[a * 3 + dyy] = okx[a] && oky[dyy];

    f2 acc[9];
#pragma unroll
    for (int jj = 0; jj < 9; ++jj) acc[jj] = f2{0.f, 0.f};

#pragma unroll 2
    for (int c = 0; c < CC; ++c) {
        f2 pv = *reinterpret_cast<const f2*>(pp);
#pragma unroll
        for (int a = 0; a < 3; ++a) {
#pragma unroll
            for (int dyy = 0; dyy < 3; ++dyy) {
                const int jj = a * 3 + dyy;
                if (okj[jj]) {
                    f2 nv = *reinterpret_cast<const f2*>(tpx[a] + (dyy - 1) * CZ);
                    acc[jj] += pv * nv;
                }
            }
            tpx[a] += cstr;
        }
        pp += cstr;
    }

    const size_t obase = (size_t)b * 27 * cstr + (size_t)x * plane
                       + (size_t)y * CZ + z2 * 2;
    const float s = 1.0f / 32.0f;
#pragma unroll
    for (int jj = 0; jj < 9; ++jj) {
        f2 v = acc[jj] * s;
        f2 gm = v; if (z2 == Z2 - 1) gm.y = 0.f;     // k=-1: zero z==47
        f2 gp = v; if (z2 == 0)      gp.x = 0.f;     // k=+1: zero z==0
        *(f2*)(corr + obase + (size_t)jj * cstr) = gm;
        *(f2*)(corr + obase + (size_t)(9 + jj) * cstr) = v;
        *(f2*)(corr + obase + (size_t)(18 + jj) * cstr) = gp;
    }
}

__device__ __forceinline__ void vel_body(
    int bid, const float* __restrict__ phi, const float* __restrict__ stm,
    float* __restrict__ vel, float* __restrict__ vphi, float* __restrict__ vstr)
{
    constexpr int TT = O / 2;                        // 47
    const int q = VEL_NWG >> 3, rr = VEL_NWG & 7;    // 1622, 2
    int xcd = bid & 7, g = bid >> 3;
    int swz = (xcd < rr) ? (xcd * (q + 1) + g) : (rr * (q + 1) + (xcd - rr) * q + g);
    int idx = swz * 256 + (int)threadIdx.x;
    if (idx >= VEL_TOTAL) return;
    int tt = idx % TT; int r2 = idx / TT;
    int j = r2 % O; r2 /= O;
    int i = r2 % O; int b = r2 / O;
    const int t = tt * 2;

    const int hp = H * H;                            // 9216
    const size_t hc = (size_t)H * hp;
    const float* ph = phi + (size_t)b * hc;
    const float* s0 = stm + (size_t)b * 3 * hc;
    const float* s1 = s0 + hc;
    const float* s2 = s1 + hc;

#define R(A, B_) ((size_t)(A) * hp + (size_t)(B_) * H + t)

    // ---- phi taps ----
    const float* p11 = ph + R(i + 1, j + 1);
    f2 p11a = *(const f2*)p11;           // t, t+1
    f2 p11b = *(const f2*)(p11 + 2);     // t+2, t+3
    float p12_1 = ph[R(i + 1, j + 2) + 1], p12_2 = ph[R(i + 1, j + 2) + 2];
    float p10_1 = ph[R(i + 1, j)     + 1], p10_2 = ph[R(i + 1, j)     + 2];
    float p21_1 = ph[R(i + 2, j + 1) + 1], p21_2 = ph[R(i + 2, j + 1) + 2];
    float p01_1 = ph[R(i,     j + 1) + 1], p01_2 = ph[R(i,     j + 1) + 2];

    float pc0 = p11a.y, pc1 = p11b.x;
    float mup0 = ((p11b.x - pc0) + (pc0 - p11a.x)) * 0.5f;
    float mup1 = ((p11b.y - pc1) + (pc1 - p11a.y)) * 0.5f;
    float mvp0 = ((p12_1 - pc0) + (pc0 - p10_1)) * 0.5f;
    float mvp1 = ((p12_2 - pc1) + (pc1 - p10_2)) * 0.5f;
    float mwp0 = ((p21_1 - pc0) + (pc0 - p01_1)) * 0.5f;
    float mwp1 = ((p21_2 - pc1) + (pc1 - p01_2)) * 0.5f;

    // ---- stream taps ----
    const float* q1_11 = s1 + R(i + 1, j + 1);
    f2 s1_11a = *(const f2*)q1_11;  f2 s1_11b = *(const f2*)(q1_11 + 2);
    const float* q1_21 = s1 + R(i + 2, j + 1);
    f2 s1_21a = *(const f2*)q1_21;  float s1_21_2 = q1_21[2];
    const float* q1_01 = s1 + R(i, j + 1);
    float s1_01_1 = q1_01[1];       f2 s1_01b = *(const f2*)(q1_01 + 2);

    const float* q0_11 = s0 + R(i + 1, j + 1);
    f2 s0_11a = *(const f2*)q0_11;  f2 s0_11b = *(const f2*)(q0_11 + 2);
    const float* q0_12 = s0 + R(i + 1, j + 2);
    f2 s0_12a = *(const f2*)q0_12;  float s0_12_2 = q0_12[2];
    const float* q0_10 = s0 + R(i + 1, j);
    float s0_10_1 = q0_10[1];       f2 s0_10b = *(const f2*)(q0_10 + 2);

    float s2_21_1 = s2[R(i + 2, j + 1) + 1], s2_21_2 = s2[R(i + 2, j + 1) + 2];
    float s2_11_1 = s2[R(i + 1, j + 1) + 1], s2_11_2 = s2[R(i + 1, j + 1) + 2];
    float s2_20_1 = s2[R(i + 2, j)     + 1], s2_20_2 = s2[R(i + 2, j)     + 2];
    float s2_10_1 = s2[R(i + 1, j)     + 1], s2_10_2 = s2[R(i + 1, j)     + 2];
    float s2_12_1 = s2[R(i + 1, j + 2) + 1], s2_12_2 = s2[R(i + 1, j + 2) + 2];
    float s2_02_1 = s2[R(i,     j + 2) + 1], s2_02_2 = s2[R(i,     j + 2) + 2];
    float s2_01_1 = s2[R(i,     j + 1) + 1], s2_01_2 = s2[R(i,     j + 1) + 2];
#undef R

    // u = d_x s1 - d_y s0 ; mu = (u(t+1)+u(t))/2
    float u0 = (s1_21a.x - s1_11a.x) - (s0_12a.x - s0_11a.x);
    float u1 = (s1_21a.y - s1_11a.y) - (s0_12a.y - s0_11a.y);
    float u2 = (s1_21_2  - s1_11b.x) - (s0_12_2  - s0_11b.x);
    float mus0 = (u1 + u0) * 0.5f;
    float mus1 = (u2 + u1) * 0.5f;

    // v = d_t s0 - d_x s2 ; mv = (v(j+1)+v(j))/2
    float v1_0 = (s0_11b.x - s0_11a.y) - (s2_21_1 - s2_11_1);
    float v0_0 = (s0_10b.x - s0_10_1)  - (s2_20_1 - s2_10_1);
    float mvs0 = (v1_0 + v0_0) * 0.5f;
    float v1_1 = (s0_11b.y - s0_11b.x) - (s2_21_2 - s2_11_2);
    float v0_1 = (s0_10b.y - s0_10b.x) - (s2_20_2 - s2_10_2);
    float mvs1 = (v1_1 + v0_1) * 0.5f;

    // w = d_y s2 - d_t s1 ; mw = (w(i+1)+w(i))/2
    float w1_0 = (s2_12_1 - s2_11_1) - (s1_11b.x - s1_11a.y);
    float w0_0 = (s2_02_1 - s2_01_1) - (s1_01b.x - s1_01_1);
    float mws0 = (w1_0 + w0_0) * 0.5f;
    float w1_1 = (s2_12_2 - s2_11_2) - (s1_11b.y - s1_11b.x);
    float w0_1 = (s2_02_2 - s2_01_2) - (s1_01b.y - s1_01b.x);
    float mws1 = (w1_1 + w0_1) * 0.5f;

    const size_t oc = (size_t)O * O * O;
    const size_t o  = ((size_t)i * O + j) * O + t;
    const size_t b3 = (size_t)b * 3;
    *(f2*)(vphi + (b3 + 0) * oc + o) = f2{mup0, mup1};
    *(f2*)(vphi + (b3 + 1) * oc + o) = f2{mvp0, mvp1};
    *(f2*)(vphi + (b3 + 2) * oc + o) = f2{mwp0, mwp1};
    *(f2*)(vstr + (b3 + 0) * oc + o) = f2{mus0, mus1};
    *(f2*)(vstr + (b3 + 1) * oc + o) = f2{mvs0, mvs1};
    *(f2*)(vstr + (b3 + 2) * oc + o) = f2{mws0, mws1};
    *(f2*)(vel + (b3 + 0) * oc + o) = f2{mup0 + mus0, mup1 + mus1};
    *(f2*)(vel + (b3 + 1) * oc + o) = f2{mvp0 + mvs0, mvp1 + mvs1};
    *(f2*)(vel + (b3 + 2) * oc + o) = f2{mwp0 + mws0, mwp1 + mws1};
}

__global__ __launch_bounds__(256) void fused_kernel(
    const float* __restrict__ prev, const float* __restrict__ nxt,
    const float* __restrict__ phi, const float* __restrict__ stm,
    float* __restrict__ corr, float* __restrict__ vel,
    float* __restrict__ vphi, float* __restrict__ vstr)
{
    int bid = blockIdx.x;
    if (bid < CORR_NWG) {
        corr_body(bid, prev, nxt, corr);
    } else {
        vel_body(bid - CORR_NWG, phi, stm, vel, vphi, vstr);
    }
}

extern "C" void kernel_launch(void* const* d_in, const int* in_sizes, int n_in,
                              void* d_out, int out_size, void* d_ws, size_t ws_size,
                              hipStream_t stream)
{
    const float* prev = (const float*)d_in[0];
    const float* nxt  = (const float*)d_in[1];
    const float* phi  = (const float*)d_in[2];
    const float* stm  = (const float*)d_in[3];

    float* out = (float*)d_out;
    const size_t corr_sz = (size_t)CB * 27 * CX * CY * CZ;   // 23,887,872
    const size_t vel_sz  = (size_t)CB * 3 * O * O * O;       // 19,934,016
    float* corr = out;
    float* vel  = out + corr_sz;
    float* vphi = vel + vel_sz;
    float* vstr = vphi + vel_sz;

    fused_kernel<<<CORR_NWG + VEL_NWG, 256, 0, stream>>>(
        prev, nxt, phi, stm, corr, vel, vphi, vstr);
}

// Round 6
// 218.394 us; speedup vs baseline: 1.1903x; 1.0412x over previous
//
#include <hip/hip_runtime.h>

// Shapes (fixed):
//   prev/next: [8, 32, 48, 48, 48] f32
//   phi:       [8, 1, 96, 96, 96] f32
//   stream:    [8, 3, 96, 96, 96] f32
// Outputs concatenated in d_out (f32): corr [8,27,48^3], vel/vel_phi/vel_stream [8,3,94^3]
//
// R6: corr inner loop rebuilt for memory-level parallelism:
//  - explicit prefetch: all 10 loads of iter c+1 issued before FMAs of iter c
//  - branch-free taps (clamped safe address + 0-scale in epilogue)
//  - u32 tap offsets vs uniform SGPR base (saddr+voffset form)
//  - __launch_bounds__(256,6): VGPR cap 85 so the prefetch set stays in regs
// vel: exact R3 body (wall-best). nt stores everywhere (R5 showed nt > normal).

typedef float f2 __attribute__((ext_vector_type(2)));

constexpr int CB = 8, CC = 32, CX = 48, CY = 48, CZ = 48;
constexpr int H = 96, O = 94;
constexpr int PLANE = CY * CZ;       // 2304
constexpr int CSTR  = CX * PLANE;    // 110592

constexpr int CORR_NWG = (CB * CX * CY * (CZ / 2)) / 256;    // 1728
constexpr int VEL_TOTAL = CB * O * O * (O / 2);              // 3,322,336
constexpr int VEL_NWG = (VEL_TOTAL + 255) / 256;             // 12978

__device__ __forceinline__ void corr_body(
    int bid, const float* __restrict__ prev, const float* __restrict__ nxt,
    float* __restrict__ corr)
{
    constexpr int Z2 = CZ / 2;                       // 24
    int swz = (bid & 7) * (CORR_NWG / 8) + (bid >> 3);  // XCD k -> batch b = k
    int idx = swz * 256 + (int)threadIdx.x;
    int z2 = idx % Z2; int r = idx / Z2;
    int y = r % CY; r /= CY;
    int x = r % CX; int b = r / CX;

    const size_t bbase = (size_t)b * CC * CSTR;
    const float* __restrict__ pbase = prev + bbase;
    const float* __restrict__ nbase = nxt + bbase;

    const int off0 = x * PLANE + y * CZ + z2 * 2;    // prev offset (u32, < 2^27)
    int offj[9];
    float scj[9];
#pragma unroll
    for (int a = 0; a < 3; ++a) {
        int xx = x + a - 1;
        bool vx = (unsigned)xx < (unsigned)CX;
#pragma unroll
        for (int d = 0; d < 3; ++d) {
            int yy = y + d - 1;
            bool ok = vx && ((unsigned)yy < (unsigned)CY);
            offj[a * 3 + d] = (ok ? xx : x) * PLANE + (ok ? yy : y) * CZ + z2 * 2;
            scj[a * 3 + d] = ok ? (1.0f / 32.0f) : 0.0f;   // invalid tap -> 0
        }
    }

    f2 acc[9];
#pragma unroll
    for (int jj = 0; jj < 9; ++jj) acc[jj] = f2{0.f, 0.f};

    // ---- software-pipelined c-loop: prefetch depth 1, branch-free ----
    const float* pc = pbase;
    const float* nc = nbase;
    f2 pA = *reinterpret_cast<const f2*>(pc + off0);
    f2 nA[9];
#pragma unroll
    for (int jj = 0; jj < 9; ++jj)
        nA[jj] = *reinterpret_cast<const f2*>(nc + offj[jj]);

#pragma unroll
    for (int c = 0; c < CC; ++c) {
        const float* pn = pc + CSTR;
        const float* nn = nc + CSTR;
        f2 pB = f2{0.f, 0.f};
        f2 nB[9];
#pragma unroll
        for (int jj = 0; jj < 9; ++jj) nB[jj] = f2{0.f, 0.f};
        if (c < CC - 1) {                             // static at full unroll
            pB = *reinterpret_cast<const f2*>(pn + off0);
#pragma unroll
            for (int jj = 0; jj < 9; ++jj)
                nB[jj] = *reinterpret_cast<const f2*>(nn + offj[jj]);
        }
#pragma unroll
        for (int jj = 0; jj < 9; ++jj) acc[jj] += pA * nA[jj];
        pA = pB;
#pragma unroll
        for (int jj = 0; jj < 9; ++jj) nA[jj] = nB[jj];
        pc = pn; nc = nn;
    }

    const size_t obase = (size_t)b * 27 * CSTR + (size_t)x * PLANE
                       + (size_t)y * CZ + z2 * 2;
#pragma unroll
    for (int jj = 0; jj < 9; ++jj) {
        f2 v = acc[jj] * scj[jj];
        f2 gm = v; if (z2 == Z2 - 1) gm.y = 0.f;     // k=-1: zero z==47
        f2 gp = v; if (z2 == 0)      gp.x = 0.f;     // k=+1: zero z==0
        __builtin_nontemporal_store(gm, (f2*)(corr + obase + (size_t)jj * CSTR));
        __builtin_nontemporal_store(v,  (f2*)(corr + obase + (size_t)(9 + jj) * CSTR));
        __builtin_nontemporal_store(gp, (f2*)(corr + obase + (size_t)(18 + jj) * CSTR));
    }
}

__device__ __forceinline__ void vel_body(
    int bid, const float* __restrict__ phi, const float* __restrict__ stm,
    float* __restrict__ vel, float* __restrict__ vphi, float* __restrict__ vstr)
{
    constexpr int TT = O / 2;                        // 47
    const int q = VEL_NWG >> 3, rr = VEL_NWG & 7;    // 1622, 2
    int xcd = bid & 7, g = bid >> 3;
    int swz = (xcd < rr) ? (xcd * (q + 1) + g) : (rr * (q + 1) + (xcd - rr) * q + g);
    int idx = swz * 256 + (int)threadIdx.x;
    if (idx >= VEL_TOTAL) return;
    int tt = idx % TT; int r2 = idx / TT;
    int j = r2 % O; r2 /= O;
    int i = r2 % O; int b = r2 / O;
    const int t = tt * 2;

    const int hp = H * H;                            // 9216
    const size_t hc = (size_t)H * hp;
    const float* ph = phi + (size_t)b * hc;
    const float* s0 = stm + (size_t)b * 3 * hc;
    const float* s1 = s0 + hc;
    const float* s2 = s1 + hc;

#define R(A, B_) ((size_t)(A) * hp + (size_t)(B_) * H + t)

    // ---- phi taps ----
    const float* p11 = ph + R(i + 1, j + 1);
    f2 p11a = *(const f2*)p11;           // t, t+1
    f2 p11b = *(const f2*)(p11 + 2);     // t+2, t+3
    float p12_1 = ph[R(i + 1, j + 2) + 1], p12_2 = ph[R(i + 1, j + 2) + 2];
    float p10_1 = ph[R(i + 1, j)     + 1], p10_2 = ph[R(i + 1, j)     + 2];
    float p21_1 = ph[R(i + 2, j + 1) + 1], p21_2 = ph[R(i + 2, j + 1) + 2];
    float p01_1 = ph[R(i,     j + 1) + 1], p01_2 = ph[R(i,     j + 1) + 2];

    float pc0 = p11a.y, pc1 = p11b.x;
    float mup0 = ((p11b.x - pc0) + (pc0 - p11a.x)) * 0.5f;
    float mup1 = ((p11b.y - pc1) + (pc1 - p11a.y)) * 0.5f;
    float mvp0 = ((p12_1 - pc0) + (pc0 - p10_1)) * 0.5f;
    float mvp1 = ((p12_2 - pc1) + (pc1 - p10_2)) * 0.5f;
    float mwp0 = ((p21_1 - pc0) + (pc0 - p01_1)) * 0.5f;
    float mwp1 = ((p21_2 - pc1) + (pc1 - p01_2)) * 0.5f;

    // ---- stream taps ----
    const float* q1_11 = s1 + R(i + 1, j + 1);
    f2 s1_11a = *(const f2*)q1_11;  f2 s1_11b = *(const f2*)(q1_11 + 2);
    const float* q1_21 = s1 + R(i + 2, j + 1);
    f2 s1_21a = *(const f2*)q1_21;  float s1_21_2 = q1_21[2];
    const float* q1_01 = s1 + R(i, j + 1);
    float s1_01_1 = q1_01[1];       f2 s1_01b = *(const f2*)(q1_01 + 2);

    const float* q0_11 = s0 + R(i + 1, j + 1);
    f2 s0_11a = *(const f2*)q0_11;  f2 s0_11b = *(const f2*)(q0_11 + 2);
    const float* q0_12 = s0 + R(i + 1, j + 2);
    f2 s0_12a = *(const f2*)q0_12;  float s0_12_2 = q0_12[2];
    const float* q0_10 = s0 + R(i + 1, j);
    float s0_10_1 = q0_10[1];       f2 s0_10b = *(const f2*)(q0_10 + 2);

    float s2_21_1 = s2[R(i + 2, j + 1) + 1], s2_21_2 = s2[R(i + 2, j + 1) + 2];
    float s2_11_1 = s2[R(i + 1, j + 1) + 1], s2_11_2 = s2[R(i + 1, j + 1) + 2];
    float s2_20_1 = s2[R(i + 2, j)     + 1], s2_20_2 = s2[R(i + 2, j)     + 2];
    float s2_10_1 = s2[R(i + 1, j)     + 1], s2_10_2 = s2[R(i + 1, j)     + 2];
    float s2_12_1 = s2[R(i + 1, j + 2) + 1], s2_12_2 = s2[R(i + 1, j + 2) + 2];
    float s2_02_1 = s2[R(i,     j + 2) + 1], s2_02_2 = s2[R(i,     j + 2) + 2];
    float s2_01_1 = s2[R(i,     j + 1) + 1], s2_01_2 = s2[R(i,     j + 1) + 2];
#undef R

    // u = d_x s1 - d_y s0 ; mu = (u(t+1)+u(t))/2
    float u0 = (s1_21a.x - s1_11a.x) - (s0_12a.x - s0_11a.x);
    float u1 = (s1_21a.y - s1_11a.y) - (s0_12a.y - s0_11a.y);
    float u2 = (s1_21_2  - s1_11b.x) - (s0_12_2  - s0_11b.x);
    float mus0 = (u1 + u0) * 0.5f;
    float mus1 = (u2 + u1) * 0.5f;

    // v = d_t s0 - d_x s2 ; mv = (v(j+1)+v(j))/2
    float v1_0 = (s0_11b.x - s0_11a.y) - (s2_21_1 - s2_11_1);
    float v0_0 = (s0_10b.x - s0_10_1)  - (s2_20_1 - s2_10_1);
    float mvs0 = (v1_0 + v0_0) * 0.5f;
    float v1_1 = (s0_11b.y - s0_11b.x) - (s2_21_2 - s2_11_2);
    float v0_1 = (s0_10b.y - s0_10b.x) - (s2_20_2 - s2_10_2);
    float mvs1 = (v1_1 + v0_1) * 0.5f;

    // w = d_y s2 - d_t s1 ; mw = (w(i+1)+w(i))/2
    float w1_0 = (s2_12_1 - s2_11_1) - (s1_11b.x - s1_11a.y);
    float w0_0 = (s2_02_1 - s2_01_1) - (s1_01b.x - s1_01_1);
    float mws0 = (w1_0 + w0_0) * 0.5f;
    float w1_1 = (s2_12_2 - s2_11_2) - (s1_11b.y - s1_11b.x);
    float w0_1 = (s2_02_2 - s2_01_2) - (s1_01b.y - s1_01b.x);
    float mws1 = (w1_1 + w0_1) * 0.5f;

    const size_t oc = (size_t)O * O * O;
    const size_t o  = ((size_t)i * O + j) * O + t;
    const size_t b3 = (size_t)b * 3;
    __builtin_nontemporal_store(f2{mup0, mup1}, (f2*)(vphi + (b3 + 0) * oc + o));
    __builtin_nontemporal_store(f2{mvp0, mvp1}, (f2*)(vphi + (b3 + 1) * oc + o));
    __builtin_nontemporal_store(f2{mwp0, mwp1}, (f2*)(vphi + (b3 + 2) * oc + o));
    __builtin_nontemporal_store(f2{mus0, mus1}, (f2*)(vstr + (b3 + 0) * oc + o));
    __builtin_nontemporal_store(f2{mvs0, mvs1}, (f2*)(vstr + (b3 + 1) * oc + o));
    __builtin_nontemporal_store(f2{mws0, mws1}, (f2*)(vstr + (b3 + 2) * oc + o));
    __builtin_nontemporal_store(f2{mup0 + mus0, mup1 + mus1}, (f2*)(vel + (b3 + 0) * oc + o));
    __builtin_nontemporal_store(f2{mvp0 + mvs0, mvp1 + mvs1}, (f2*)(vel + (b3 + 1) * oc + o));
    __builtin_nontemporal_store(f2{mwp0 + mws0, mwp1 + mws1}, (f2*)(vel + (b3 + 2) * oc + o));
}

__global__ __launch_bounds__(256, 6) void fused_kernel(
    const float* __restrict__ prev, const float* __restrict__ nxt,
    const float* __restrict__ phi, const float* __restrict__ stm,
    float* __restrict__ corr, float* __restrict__ vel,
    float* __restrict__ vphi, float* __restrict__ vstr)
{
    int bid = blockIdx.x;
    if (bid < CORR_NWG) {
        corr_body(bid, prev, nxt, corr);
    } else {
        vel_body(bid - CORR_NWG, phi, stm, vel, vphi, vstr);
    }
}

extern "C" void kernel_launch(void* const* d_in, const int* in_sizes, int n_in,
                              void* d_out, int out_size, void* d_ws, size_t ws_size,
                              hipStream_t stream)
{
    const float* prev = (const float*)d_in[0];
    const float* nxt  = (const float*)d_in[1];
    const float* phi  = (const float*)d_in[2];
    const float* stm  = (const float*)d_in[3];

    float* out = (float*)d_out;
    const size_t corr_sz = (size_t)CB * 27 * CX * CY * CZ;   // 23,887,872
    const size_t vel_sz  = (size_t)CB * 3 * O * O * O;       // 19,934,016
    float* corr = out;
    float* vel  = out + corr_sz;
    float* vphi = vel + vel_sz;
    float* vstr = vphi + vel_sz;

    fused_kernel<<<CORR_NWG + VEL_NWG, 256, 0, stream>>>(
        prev, nxt, phi, stm, corr, vel, vphi, vstr);
}